// Round 1
// baseline (231.742 us; speedup 1.0000x reference)
//
#include <hip/hip_runtime.h>

typedef __bf16 bf16x8 __attribute__((ext_vector_type(8)));
typedef float f32x4 __attribute__((ext_vector_type(4)));

#define MFMA16(a,b,c) __builtin_amdgcn_mfma_f32_16x16x32_bf16(a,b,c,0,0,0)

__device__ __forceinline__ unsigned short f2b(float x){
  __bf16 b = (__bf16)x;
  return __builtin_bit_cast(unsigned short, b);
}

// ---------------- kernel 0: pack W^T bf16 [192][768] ----------------
__global__ __launch_bounds__(256) void pack_w(const float* __restrict__ Wq,
                                              const float* __restrict__ Wk,
                                              const float* __restrict__ Wv,
                                              unsigned short* __restrict__ Wt){
  int idx = blockIdx.x*256 + threadIdx.x;      // 192*768 = 147456 = 576*256
  int n = idx/768, c = idx - n*768;
  const float* W = (n < 64) ? Wq : ((n < 128) ? Wk : Wv);
  Wt[n*768 + c] = f2b(W[c*64 + (n & 63)]);
}

// ---------------- kernel 1: QKV projection ----------------
// M=16384 rows of x, N=192 (Q|K|V), K=768. wg=256thr (4 waves x 16 rows).
// Outputs: Qb,Kb bf16 [b][t][64]; Vt bf16 [b][64][t] (pre-transposed).
__global__ __launch_bounds__(256) void qkv_proj(const float* __restrict__ x,
                                                const unsigned short* __restrict__ Wt,
                                                unsigned short* __restrict__ Qb,
                                                unsigned short* __restrict__ Kb,
                                                unsigned short* __restrict__ Vt){
  __shared__ __attribute__((aligned(16))) unsigned short Wl[192*72]; // pad 64->72: 2-way banks (free)
  const int tid = threadIdx.x;
  const int w = tid>>6, l = tid&63, quad = l>>4, lr = l&15;
  const int row0 = blockIdx.x*64;
  f32x4 acc[12];
#pragma unroll
  for(int i=0;i<12;i++) acc[i] = (f32x4)0.0f;
  const int arow = row0 + w*16 + lr;           // A-frag row (m = lane&15)
  for(int kk=0;kk<12;kk++){                    // 12 chunks of BK=64
    if(kk) __syncthreads();
#pragma unroll
    for(int i=0;i<6;i++){                      // stage Wt[0:192][kk*64:+64): 1536 x 16B
      int p = tid + 256*i;
      int r = p>>3, o = (p&7)*8;
      *(int4*)&Wl[r*72 + o] = *(const int4*)&Wt[r*768 + kk*64 + o];
    }
    __syncthreads();
    const float* xr = x + (size_t)arow*768 + kk*64 + quad*8;
#pragma unroll
    for(int ks=0;ks<2;ks++){
      f32x4 x0 = *(const f32x4*)(xr + ks*32);
      f32x4 x1 = *(const f32x4*)(xr + ks*32 + 4);
      bf16x8 a;
#pragma unroll
      for(int j=0;j<4;j++){ a[j] = (__bf16)x0[j]; a[4+j] = (__bf16)x1[j]; }
#pragma unroll
      for(int nt=0;nt<12;nt++){
        bf16x8 bfr = *(const bf16x8*)&Wl[(nt*16+lr)*72 + ks*32 + quad*8];
        acc[nt] = MFMA16(a, bfr, acc[nt]);
      }
    }
  }
  // epilogue: C-layout row = quad*4+r, col = nt*16+lr
  const int trow = row0 + w*16 + quad*4;
  const int b_ = trow>>12, t_ = trow&4095;     // whole wg in one batch
#pragma unroll
  for(int nt=0;nt<4;nt++){
#pragma unroll
    for(int r=0;r<4;r++){
      Qb[((size_t)(b_*4096 + t_ + r))*64 + nt*16 + lr] = f2b(acc[nt][r]);
      Kb[((size_t)(b_*4096 + t_ + r))*64 + nt*16 + lr] = f2b(acc[4+nt][r]);
    }
    int h = nt*16 + lr;
    ushort4 pk;
    pk.x = f2b(acc[8+nt][0]); pk.y = f2b(acc[8+nt][1]);
    pk.z = f2b(acc[8+nt][2]); pk.w = f2b(acc[8+nt][3]);
    *(ushort4*)&Vt[((size_t)(b_*64 + h))*4096 + t_] = pk;   // 4 consecutive t, 8B store
  }
}

// ---------------- kernel 2: causal flash attention ----------------
// wg = 64 queries (wave w owns 16), grid = (T/64, B). K/V tiles of 64 keys in LDS.
__global__ __launch_bounds__(256) void attn(const unsigned short* __restrict__ Qb,
                                            const unsigned short* __restrict__ Kb,
                                            const unsigned short* __restrict__ Vt,
                                            float* __restrict__ out){
  __shared__ __attribute__((aligned(16))) unsigned short Kl[64*72];     // [key][h]
  __shared__ __attribute__((aligned(16))) unsigned short Vl[64*72];     // [h][key] (V^T)
  __shared__ __attribute__((aligned(16))) unsigned short Pl[4][16*72];  // per-wave P
  const int tid = threadIdx.x;
  const int w = tid>>6, l = tid&63, quad = l>>4, lr = l&15;
  const int qtile = blockIdx.x, b = blockIdx.y;
  const int qb = qtile*64;
  const int qrow = qb + w*16 + lr;             // A-frag row
  const unsigned short* qptr = Qb + ((size_t)(b*4096 + qrow))*64 + quad*8;
  const bf16x8 aq0 = *(const bf16x8*)(qptr);
  const bf16x8 aq1 = *(const bf16x8*)(qptr + 32);
  f32x4 o_[4];
#pragma unroll
  for(int i=0;i<4;i++) o_[i] = (f32x4)0.0f;
  float mi[4] = {-3.0e38f,-3.0e38f,-3.0e38f,-3.0e38f};
  float li[4] = {0.f,0.f,0.f,0.f};
  const int qg = qb + w*16 + quad*4;           // C-layout row base (query)
  const float sc = 0.03608439182435161f;       // 1/sqrt(768)
  const int nkt = qtile + 1;
  for(int kt=0; kt<nkt; kt++){
    if(kt) __syncthreads();
#pragma unroll
    for(int i=0;i<2;i++){                      // stage K tile + V^T tile (512 x 16B)
      int p = tid + 256*i;
      int r = p>>3, oo = (p&7)*8;
      *(int4*)&Kl[r*72+oo] = *(const int4*)&Kb[((size_t)(b*4096 + kt*64 + r))*64 + oo];
      *(int4*)&Vl[r*72+oo] = *(const int4*)&Vt[((size_t)(b*64 + r))*4096 + kt*64 + oo];
    }
    __syncthreads();
    // S = Q K^T : 4 column tiles of 16 keys, K-dim 64 = 2 MFMA steps
    f32x4 s[4];
#pragma unroll
    for(int ct=0;ct<4;ct++){
      bf16x8 b0 = *(const bf16x8*)&Kl[(ct*16+lr)*72 + quad*8];
      bf16x8 b1 = *(const bf16x8*)&Kl[(ct*16+lr)*72 + 32 + quad*8];
      f32x4 z = (f32x4)0.0f;
      z = MFMA16(aq0, b0, z);
      s[ct] = MFMA16(aq1, b1, z);
    }
    // scale + causal mask + online softmax (row = quad*4+r lives in 16 lanes of this quad)
    float mx[4] = {-3.0e38f,-3.0e38f,-3.0e38f,-3.0e38f};
#pragma unroll
    for(int ct=0;ct<4;ct++){
      int kg = kt*64 + ct*16 + lr;
#pragma unroll
      for(int r=0;r<4;r++){
        float v = s[ct][r]*sc;
        v = (kg > qg + r) ? -3.0e38f : v;
        s[ct][r] = v;
        mx[r] = fmaxf(mx[r], v);
      }
    }
#pragma unroll
    for(int r=0;r<4;r++){
#pragma unroll
      for(int off=1; off<16; off<<=1) mx[r] = fmaxf(mx[r], __shfl_xor(mx[r], off, 16));
      float mn = fmaxf(mi[r], mx[r]);
      mx[r] = __expf(mi[r]-mn);                // mx becomes alpha
      mi[r] = mn;
    }
    float rs[4] = {0.f,0.f,0.f,0.f};
#pragma unroll
    for(int ct=0;ct<4;ct++){
#pragma unroll
      for(int r=0;r<4;r++){
        float p = __expf(s[ct][r]-mi[r]);
        s[ct][r] = p;
        rs[r] += p;
      }
    }
#pragma unroll
    for(int r=0;r<4;r++){
#pragma unroll
      for(int off=1; off<16; off<<=1) rs[r] += __shfl_xor(rs[r], off, 16);
      li[r] = li[r]*mx[r] + rs[r];
    }
#pragma unroll
    for(int nt=0;nt<4;nt++){
#pragma unroll
      for(int r=0;r<4;r++) o_[nt][r] *= mx[r];
    }
    // P: C-layout -> LDS [query][key] (A-layout source). Per-wave buffer, wave-synchronous.
#pragma unroll
    for(int ct=0;ct<4;ct++){
#pragma unroll
      for(int r=0;r<4;r++) Pl[w][(quad*4+r)*72 + ct*16 + lr] = f2b(s[ct][r]);
    }
    asm volatile("s_waitcnt lgkmcnt(0)" ::: "memory");
    // O += P V : A = P[16q x 32k], B = V[32k x 16h] read from V^T rows
#pragma unroll
    for(int ks=0;ks<2;ks++){
      bf16x8 ap = *(const bf16x8*)&Pl[w][lr*72 + ks*32 + quad*8];
#pragma unroll
      for(int nt=0;nt<4;nt++){
        bf16x8 bv = *(const bf16x8*)&Vl[(nt*16+lr)*72 + ks*32 + quad*8];
        o_[nt] = MFMA16(ap, bv, o_[nt]);
      }
    }
  }
  // epilogue: out[b][qg+r][nt*16+lr] = O/l
#pragma unroll
  for(int r=0;r<4;r++){
    float inv = 1.0f/li[r];
#pragma unroll
    for(int nt=0;nt<4;nt++){
      out[((size_t)(b*4096 + qg + r))*64 + nt*16 + lr] = o_[nt][r]*inv;
    }
  }
}

extern "C" void kernel_launch(void* const* d_in, const int* in_sizes, int n_in,
                              void* d_out, int out_size, void* d_ws, size_t ws_size,
                              hipStream_t stream){
  const float* x  = (const float*)d_in[0];
  const float* Wq = (const float*)d_in[1];
  const float* Wk = (const float*)d_in[2];
  const float* Wv = (const float*)d_in[3];
  float* out = (float*)d_out;
  char* ws = (char*)d_ws;
  unsigned short* Wt = (unsigned short*)(ws);                          // 294912 B
  unsigned short* Qb = (unsigned short*)(ws + (1u<<19));               // 2 MB
  unsigned short* Kb = (unsigned short*)(ws + (1u<<19) + (1u<<21));    // 2 MB
  unsigned short* Vt = (unsigned short*)(ws + (1u<<19) + (2u<<21));    // 2 MB
  hipLaunchKernelGGL(pack_w,   dim3(576),   dim3(256), 0, stream, Wq, Wk, Wv, Wt);
  hipLaunchKernelGGL(qkv_proj, dim3(256),   dim3(256), 0, stream, x, Wt, Qb, Kb, Vt);
  hipLaunchKernelGGL(attn,     dim3(64, 4), dim3(256), 0, stream, Qb, Kb, Vt, out);
}